// Round 19
// baseline (107.064 us; speedup 1.0000x reference)
//
#include <hip/hip_runtime.h>
#include <math.h>

#define T_STEPS 1000
#define B_ROWS 65536
#define N_FCAT 24
#define N_DCAT 298
#define NUM_NUM 16
#define MO_STRIDE 314
#define NKID 14
#define NEGL -69.07755278982137f   // log(float32(1e-30))
#define NINF -1e38f

__constant__ int c_numc[N_FCAT] = {2,2,3,4,5,6,8,10,10,12,16,16,20,24,32,40,2,3,4,5,6,8,10,50};
__constant__ int c_kval[NKID]   = {2,3,4,5,6,8,10,12,16,20,24,32,40,50};

// 4-lane quad descriptors (qsel = lane16>>2)
__constant__ int qAK[4]   = {10,10,10,8};
__constant__ int qAOFF[4] = {30,40,238,22};
__constant__ int qAKID[4] = {6,6,6,5};
__constant__ int qAF[4]   = {7,8,22,6};

__constant__ int qBK[4]   = {8,6,6,2};
__constant__ int qBOFF[4] = {230,16,224,210};
__constant__ int qBKID[4] = {5,4,4,0};
__constant__ int qBF[4]   = {21,5,20,16};

// 2-lane duo descriptors (osel = lane16>>1): 8 smallest features in one block
__constant__ int dK[8]   = {5,5,4,4,3,3,2,2};
__constant__ int dOFF[8] = {11,219,7,215,4,212,0,2};
__constant__ int dKID[8] = {3,3,2,2,1,1,0,0};
__constant__ int dF[8]   = {4,19,3,18,2,17,0,1};

// persistent module-owned tables, rebuilt deterministically every launch
__device__ float  g_sched[4*T_STEPS];      // LA | L1A | LCA | L1CA
__device__ float  g_ecap[T_STEPS];         // exp(LCA[t-1]) (1.0 at t=0)
__device__ float4 g_tab4[T_STEPS*NKID*3];  // per (t,kidx): 12 floats
__device__ float  g_klp;                   // sum over features of kl_prior

__device__ __forceinline__ float lae(float a, float b) {   // precise f32 (argmax path)
  float m = fmaxf(a, b);
  return m + logf(expf(a - m) + expf(b - m));
}
__device__ __forceinline__ double lad(double a, double b) {
  double m = fmax(a, b);
  return m + log(exp(a - m) + exp(b - m));
}

__global__ void build_sched_kernel() {
  __shared__ double sh[1024];
  int i = threadIdx.x;
  double la = 0.0;
  if (i < T_STEPS) {
    const double PI = 3.14159265358979323846;
    double u0 = (double)i / 1000.0, u1 = (double)(i + 1) / 1000.0;
    double c0 = cos((u0 + 0.008) / 1.008 * PI * 0.5);
    double c1 = cos((u1 + 0.008) / 1.008 * PI * 0.5);
    double beta = 1.0 - (c1 * c1) / (c0 * c0);
    if (beta > 0.2) beta = 0.2;
    la = log(1.0 - beta);
  }
  sh[i] = la;
  __syncthreads();
  double run = la;
  for (int ofs = 1; ofs < 1024; ofs <<= 1) {
    double add = (i >= ofs) ? sh[i - ofs] : 0.0;
    __syncthreads();
    run += add;
    sh[i] = run;
    __syncthreads();
  }
  if (i < T_STEPS) {
    g_sched[i]               = (float)la;
    g_sched[T_STEPS + i]     = (float)log(-expm1(la));
    g_sched[2 * T_STEPS + i] = (float)run;
    g_sched[3 * T_STEPS + i] = (float)log(-expm1(run));
  }
}

__global__ void build_tab_kernel() {
  int e = blockIdx.x * blockDim.x + threadIdx.x;
  if (e < T_STEPS * NKID) {
    int t = e / NKID, k = e - t * NKID;
    bool t0 = (t == 0);
    int tm1 = t0 ? 0 : t - 1;
    float la = g_sched[t], l1a = g_sched[T_STEPS + t];
    float lca = g_sched[2 * T_STEPS + t], l1ca = g_sched[3 * T_STEPS + t];
    float lca_p = g_sched[2 * T_STEPS + tm1], l1ca_p = g_sched[3 * T_STEPS + tm1];
    float logK = (float)log((double)c_kval[k]);
    // ---- argmax-critical: identical f32 sequence to the verified round-1 kernel ----
    float cb_t = l1ca - logK;
    float ev_h = lae(lca, cb_t);
    float ev_n = lae(NEGL + lca, cb_t);
    // ---- value path: double precision ----
    double cb1 = (double)l1a - (double)logK;
    double q1h = lad((double)la, cb1);
    double q1n = lad((double)NEGL + (double)la, cb1);
    double cbp = (double)l1ca_p - (double)logK;
    double levth = t0 ? 0.0 : lad((double)lca_p, cbp);
    double levtn = t0 ? (double)NEGL : lad((double)NEGL + (double)lca_p, cbp);
    float4* o = g_tab4 + e * 3;
    o[0] = make_float4(ev_h, ev_n, (float)q1h, (float)q1n);
    o[1] = make_float4((float)exp(q1h), (float)exp(q1n), (float)exp(levth), (float)exp(levtn));
    o[2] = make_float4((float)levth, (float)levtn, t0 ? 0.f : (float)exp(cbp), 0.f);
    if (k == 0) g_ecap[t] = t0 ? 1.f : (float)exp((double)lca_p);
  }
  if (e == 0) {
    double lcaT = g_sched[2 * T_STEPS + T_STEPS - 1];
    double l1caT = g_sched[3 * T_STEPS + T_STEPS - 1];
    double s = 0.0;
    for (int f = 0; f < N_FCAT; ++f) {
      double logK = log((double)c_numc[f]);
      double cbT = l1caT - logK;
      double qh = lad(lcaT, cbT);
      double qn = lad((double)NEGL + lcaT, cbT);
      s += exp(qh) * (qh + logK) + (double)(c_numc[f] - 1) * exp(qn) * (qn + logK);
    }
    g_klp = (float)s;
  }
}

// ---- DPP reductions. ctl is a TEMPLATE parameter (mov_dpp needs an immediate).
// 8-lane: xor1 (0xB1) + xor2 (0x4E) + row_half_mirror (0x141). 4-lane: xor1 +
// xor2. 2-lane: xor1 only. All strictly within their lane group. ----
template <int CTL>
__device__ __forceinline__ float dpp_add(float v) {
  return v + __int_as_float(__builtin_amdgcn_mov_dpp(__float_as_int(v), CTL, 0xF, 0xF, true));
}
__device__ __forceinline__ float osum(float v) {
  v = dpp_add<0xB1>(v); v = dpp_add<0x4E>(v); v = dpp_add<0x141>(v);
  return v;
}
__device__ __forceinline__ float qsum4(float v) {
  v = dpp_add<0xB1>(v); v = dpp_add<0x4E>(v);
  return v;
}
__device__ __forceinline__ float dsum2(float v) {
  return dpp_add<0xB1>(v);
}
template <int CTL>
__device__ __forceinline__ void argmax_step(float& smax, int& jm) {
  float os = __int_as_float(__builtin_amdgcn_mov_dpp(__float_as_int(smax), CTL, 0xF, 0xF, true));
  int   oj = __builtin_amdgcn_mov_dpp(jm, CTL, 0xF, 0xF, true);
  if (os > smax || (os == smax && oj < jm)) { smax = os; jm = oj; }
}
__device__ __forceinline__ void oargmax(float& smax, int& jm) {
  argmax_step<0xB1>(smax, jm); argmax_step<0x4E>(smax, jm); argmax_step<0x141>(smax, jm);
}
__device__ __forceinline__ void qargmax4(float& smax, int& jm) {
  argmax_step<0xB1>(smax, jm); argmax_step<0x4E>(smax, jm);
}
__device__ __forceinline__ void dargmax2(float& smax, int& jm) {
  argmax_step<0xB1>(smax, jm);
}
__device__ __forceinline__ float mirror16_add(float v) { return dpp_add<0x140>(v); }
__device__ __forceinline__ float halfmirror_add(float v) { return dpp_add<0x141>(v); }
__device__ __forceinline__ float xor2_add(float v) { return dpp_add<0x4E>(v); }

// Generic packed-feature body: LANES lanes per feature (8, 4, or 2),
// compile-time NJ, runtime K/off/h/table (group-selected by caller).
// CACHE=false (used only for the NJ7 (50|40) block) skips the persistent
// exp-cache: pass 2 reloads x (L1-hot) and recomputes __expf -- identical
// input -> identical value; trims ~7 VGPR at the kernel's register peak.
// Element arithmetic and decision path (clamp -> precise logf gumbel ->
// score select -> ascending-j strict-max, min-index cross-lane tiebreak)
// bit-identical to all passing rounds; argmax is partition-independent.
template <int LANES, int NJ, bool CACHE = true>
__device__ __forceinline__ float packed_body(int g, int K, int off, int h, bool t0, float ecap,
                                             const float* __restrict__ mocat,
                                             const float* __restrict__ urow,
                                             const float4* __restrict__ tb)
{
  float4 ta = tb[0], tbv = tb[1], tc = tb[2];
  float ev_h = ta.x, ev_n = ta.y, q1h = ta.z, q1n = ta.w;
  float q1he = tbv.x, q1ne = tbv.y, eth = tbv.z, etn = tbv.w;
  float levth = tc.x, levtn = tc.y, cbpe = tc.z;

  float xv[CACHE ? NJ : 1];
  if (CACHE) {
    #pragma unroll
    for (int jj = 0; jj < NJ; ++jj) {
      int j = jj * LANES + g;
      int jc = (j < K) ? j : (K - 1);
      xv[jj] = mocat[off + jc];
    }
  }

  // ---- pass 1: sum exp(model_out) + gumbel-score argmax ----
  float s1 = 0.f, smax = NINF;
  int jm = 0x7fffffff;
  #pragma unroll
  for (int jj = 0; jj < NJ; ++jj) {
    int j = jj * LANES + g;
    int jc = (j < K) ? j : (K - 1);
    bool in = (j < K);
    float x = CACHE ? xv[jj] : mocat[off + jc];
    float e = __expf(x);
    if (CACHE) xv[jj] = e;                    // cache exp for pass 2
    s1 += in ? e : 0.f;
    float u = urow[off + jc];
    u = fminf(fmaxf(u, 1e-30f), 1.0f);
    float gum = -logf(-logf(u));
    float sc = ((j == h) ? ev_h : ev_n) + gum;
    if (in && sc > smax) { smax = sc; jm = j; }
  }
  if (LANES == 8)      { s1 = osum(s1);  oargmax(smax, jm); }
  else if (LANES == 4) { s1 = qsum4(s1); qargmax4(smax, jm); }
  else                 { s1 = dsum2(s1); dargmax2(smax, jm); }

  float ca = ecap * __builtin_amdgcn_rcpf(s1);  // exp(lca_{t-1}) / sum(exp(mocat))

  // ---- pass 2: E_j = exp(lev_m_j); linear-space accumulation ----
  float Sm = 0.f, Bv = 0.f, lmh = 0.f;
  #pragma unroll
  for (int jj = 0; jj < NJ; ++jj) {
    int j = jj * LANES + g;
    int jc = (j < K) ? j : (K - 1);
    bool in = (j < K);
    float e = CACHE ? xv[jj] : __expf(mocat[off + jc]);
    float E = fmaf(e, ca, cbpe);             // e^{lr+lca_p} + e^{cb_p}
    float lm = __logf(E);                    // lev_m_j
    float qe = (j == jm) ? q1he : q1ne;      // e^{q1_j}
    Sm = in ? fmaf(E, qe, Sm) : Sm;          // sum e^{un_m}
    float c = ((j == h) ? eth : etn) * qe;   // e^{un_t_j}
    Bv = in ? fmaf(c, lm, Bv) : Bv;          // sum e^{un_t} * lev_m
    lmh += (in && j == h) ? lm : 0.f;
  }
  if (LANES == 8)      { Sm = osum(Sm);  Bv = osum(Bv);  lmh = osum(lmh); }
  else if (LANES == 4) { Sm = qsum4(Sm); Bv = qsum4(Bv); lmh = qsum4(lmh); }
  else                 { Sm = dsum2(Sm); Bv = dsum2(Bv); lmh = dsum2(lmh); }

  float lse_m = __logf(Sm);
  bool hm = (h == jm);
  float Kf2 = (float)K - 2.f + (hm ? 1.f : 0.f);
  float coefH = eth * (hm ? q1he : q1ne);
  float coefJ = hm ? 0.f : etn * q1he;
  float cn = etn * q1ne;
  float A  = cn * levtn * Kf2 + coefH * levth + coefJ * levtn;  // sum e^{un_t} * levt
  float St = cn * Kf2 + coefH + coefJ;                          // sum e^{un_t}
  float kl = (A - Bv) * __builtin_amdgcn_rcpf(St) - __logf(St) + lse_m;
  float unh = lmh + (hm ? q1h : q1n);
  float dec = lse_m - unh;
  return t0 ? dec : kl;
}

__global__ __launch_bounds__(256) void gmd_kernel(
    const int* __restrict__ xci, const int* __restrict__ tarr,
    const float* __restrict__ noise, const float* __restrict__ ucat,
    const float* __restrict__ mo, float* __restrict__ out)
{
  int tid = blockIdx.x * blockDim.x + threadIdx.x;
  int row    = tid >> 4;       // 16 threads per row
  int lane16 = tid & 15;
  int g      = tid & 7;        // position within 8-lane group
  int g4     = tid & 3;        // position within 4-lane quad
  int g2     = tid & 1;        // position within 2-lane duo
  int sel    = (lane16 >> 3);  // pair select 0..1
  int qsel   = (lane16 >> 2);  // quad select 0..3
  int osel   = (lane16 >> 1);  // duo select 0..7
  if (row >= B_ROWS) return;

  int t = tarr[row];
  bool t0 = (t == 0);
  float ecap = g_ecap[t];
  const float4* tabt = g_tab4 + (size_t)t * NKID * 3;
  const int* xrow = xci + (size_t)row * N_FCAT;

  const float* morow = mo + (size_t)row * MO_STRIDE;
  const float* mocat = morow + NUM_NUM;
  const float* urow  = ucat + (size_t)row * N_DCAT;

  // Gaussian part: 1 of 16 elements per lane
  float gauss;
  {
    float d = noise[row * NUM_NUM + lane16] - morow[lane16];
    gauss = d * d;
  }

  // ---- 8-lane pairs: (32|24) NJ4; (20|16) NJ3 (was forced NJ4 by the shared
  // loop in r18 -- split saves 1 element-iter); (16|12) NJ2; (50|40) NJ7
  // no-cache (register-peak trim) ----
  float multi8 = 0.f;
  multi8 += packed_body<8,4>(g, sel ? 24 : 32, sel ? 114 : 138, xrow[sel ? 13 : 14],
                             t0, ecap, mocat, urow, tabt + (sel ? 10 : 11) * 3);
  multi8 += packed_body<8,3>(g, sel ? 16 : 20, sel ? 62 : 94, xrow[sel ? 10 : 12],
                             t0, ecap, mocat, urow, tabt + (sel ? 8 : 9) * 3);
  multi8 += packed_body<8,2>(g, sel ? 12 : 16, sel ? 50 : 78, xrow[sel ? 9 : 11],
                             t0, ecap, mocat, urow, tabt + (sel ? 7 : 8) * 3);
  multi8 += packed_body<8,7,false>(g, sel ? 40 : 50, sel ? 170 : 248, xrow[sel ? 15 : 23],
                                   t0, ecap, mocat, urow, tabt + (sel ? 12 : 13) * 3);

  // ---- 4-lane quads: (10,10,10,8) NJ3; (8,6,6,2) NJ2 ----
  float multi4 = 0.f;
  multi4 += packed_body<4,3>(g4, qAK[qsel], qAOFF[qsel], xrow[qAF[qsel]],
                             t0, ecap, mocat, urow, tabt + qAKID[qsel] * 3);
  multi4 += packed_body<4,2>(g4, qBK[qsel], qBOFF[qsel], xrow[qBF[qsel]],
                             t0, ecap, mocat, urow, tabt + qBKID[qsel] * 3);

  // ---- 2-lane duos: (5,5,4,4,3,3,2,2) NJ3 -- one block, 8 features ----
  float multi2 = packed_body<2,3>(g2, dK[osel], dOFF[osel], xrow[dF[osel]],
                                  t0, ecap, mocat, urow, tabt + dKID[osel] * 3);

  // ---- combines (each partial held group-uniform; merge up the hierarchy) ----
  multi8 = mirror16_add(multi8);                      // A + B groups
  multi4 = mirror16_add(halfmirror_add(multi4));      // 4 quads
  multi2 = mirror16_add(halfmirror_add(xor2_add(multi2)));  // 8 duos
  float multi = multi8 + multi4 + multi2;

  gauss = osum(gauss);                  // within-8 sums
  gauss = mirror16_add(gauss);          // + other 8 -> all 16 elements

  if (lane16 == 0) out[row] = (multi * 1000.f + g_klp) / 24.f + gauss / 16.f;
}

extern "C" void kernel_launch(void* const* d_in, const int* in_sizes, int n_in,
                              void* d_out, int out_size, void* d_ws, size_t ws_size,
                              hipStream_t stream) {
  const int*   xci   = (const int*)d_in[0];
  const int*   tarr  = (const int*)d_in[1];
  const float* noise = (const float*)d_in[2];
  const float* ucat  = (const float*)d_in[3];
  const float* mo    = (const float*)d_in[4];
  float* out = (float*)d_out;
  (void)d_ws; (void)ws_size;

  hipLaunchKernelGGL(build_sched_kernel, dim3(1), dim3(1024), 0, stream);
  hipLaunchKernelGGL(build_tab_kernel, dim3((T_STEPS * NKID + 255) / 256), dim3(256), 0, stream);
  hipLaunchKernelGGL(gmd_kernel, dim3((B_ROWS * 16) / 256), dim3(256), 0, stream,
                     xci, tarr, noise, ucat, mo, out);
}

// Round 20
// 100.398 us; speedup vs baseline: 1.0664x; 1.0664x over previous
//
#include <hip/hip_runtime.h>
#include <math.h>

#define T_STEPS 1000
#define B_ROWS 65536
#define N_FCAT 24
#define N_DCAT 298
#define NUM_NUM 16
#define MO_STRIDE 314
#define NKID 14
#define NEGL -69.07755278982137f   // log(float32(1e-30))
#define NINF -1e38f

__constant__ int c_numc[N_FCAT] = {2,2,3,4,5,6,8,10,10,12,16,16,20,24,32,40,2,3,4,5,6,8,10,50};
__constant__ int c_kval[NKID]   = {2,3,4,5,6,8,10,12,16,20,24,32,40,50};

// 8-lane pair descriptors (sel = lane16>>3)  [r18 structure: KEEP the loop]
__constant__ int p4K[2][2]   = {{32,24},{20,16}};
__constant__ int p4OFF[2][2] = {{138,114},{94,62}};
__constant__ int p4KID[2][2] = {{11,10},{9,8}};
__constant__ int p4F[2][2]   = {{14,13},{12,10}};

// 4-lane quad descriptors (qsel = lane16>>2)
__constant__ int qAK[4]   = {10,10,10,8};
__constant__ int qAOFF[4] = {30,40,238,22};
__constant__ int qAKID[4] = {6,6,6,5};
__constant__ int qAF[4]   = {7,8,22,6};

__constant__ int qBK[4]   = {8,6,6,2};
__constant__ int qBOFF[4] = {230,16,224,210};
__constant__ int qBKID[4] = {5,4,4,0};
__constant__ int qBF[4]   = {21,5,20,16};

// 2-lane duo descriptors (osel = lane16>>1): 8 smallest features in one block
__constant__ int dK[8]   = {5,5,4,4,3,3,2,2};
__constant__ int dOFF[8] = {11,219,7,215,4,212,0,2};
__constant__ int dKID[8] = {3,3,2,2,1,1,0,0};
__constant__ int dF[8]   = {4,19,3,18,2,17,0,1};

// persistent module-owned tables, rebuilt deterministically every launch
__device__ float  g_sched[4*T_STEPS];      // LA | L1A | LCA | L1CA
__device__ float  g_ecap[T_STEPS];         // exp(LCA[t-1]) (1.0 at t=0)
__device__ float4 g_tab4[T_STEPS*NKID*3];  // per (t,kidx): 12 floats
__device__ float  g_klp;                   // sum over features of kl_prior

__device__ __forceinline__ float lae(float a, float b) {   // precise f32 (argmax path)
  float m = fmaxf(a, b);
  return m + logf(expf(a - m) + expf(b - m));
}
__device__ __forceinline__ double lad(double a, double b) {
  double m = fmax(a, b);
  return m + log(exp(a - m) + exp(b - m));
}

__global__ void build_sched_kernel() {
  __shared__ double sh[1024];
  int i = threadIdx.x;
  double la = 0.0;
  if (i < T_STEPS) {
    const double PI = 3.14159265358979323846;
    double u0 = (double)i / 1000.0, u1 = (double)(i + 1) / 1000.0;
    double c0 = cos((u0 + 0.008) / 1.008 * PI * 0.5);
    double c1 = cos((u1 + 0.008) / 1.008 * PI * 0.5);
    double beta = 1.0 - (c1 * c1) / (c0 * c0);
    if (beta > 0.2) beta = 0.2;
    la = log(1.0 - beta);
  }
  sh[i] = la;
  __syncthreads();
  double run = la;
  for (int ofs = 1; ofs < 1024; ofs <<= 1) {
    double add = (i >= ofs) ? sh[i - ofs] : 0.0;
    __syncthreads();
    run += add;
    sh[i] = run;
    __syncthreads();
  }
  if (i < T_STEPS) {
    g_sched[i]               = (float)la;
    g_sched[T_STEPS + i]     = (float)log(-expm1(la));
    g_sched[2 * T_STEPS + i] = (float)run;
    g_sched[3 * T_STEPS + i] = (float)log(-expm1(run));
  }
}

__global__ void build_tab_kernel() {
  int e = blockIdx.x * blockDim.x + threadIdx.x;
  if (e < T_STEPS * NKID) {
    int t = e / NKID, k = e - t * NKID;
    bool t0 = (t == 0);
    int tm1 = t0 ? 0 : t - 1;
    float la = g_sched[t], l1a = g_sched[T_STEPS + t];
    float lca = g_sched[2 * T_STEPS + t], l1ca = g_sched[3 * T_STEPS + t];
    float lca_p = g_sched[2 * T_STEPS + tm1], l1ca_p = g_sched[3 * T_STEPS + tm1];
    float logK = (float)log((double)c_kval[k]);
    // ---- argmax-critical: identical f32 sequence to the verified round-1 kernel ----
    float cb_t = l1ca - logK;
    float ev_h = lae(lca, cb_t);
    float ev_n = lae(NEGL + lca, cb_t);
    // ---- value path: double precision ----
    double cb1 = (double)l1a - (double)logK;
    double q1h = lad((double)la, cb1);
    double q1n = lad((double)NEGL + (double)la, cb1);
    double cbp = (double)l1ca_p - (double)logK;
    double levth = t0 ? 0.0 : lad((double)lca_p, cbp);
    double levtn = t0 ? (double)NEGL : lad((double)NEGL + (double)lca_p, cbp);
    float4* o = g_tab4 + e * 3;
    o[0] = make_float4(ev_h, ev_n, (float)q1h, (float)q1n);
    o[1] = make_float4((float)exp(q1h), (float)exp(q1n), (float)exp(levth), (float)exp(levtn));
    o[2] = make_float4((float)levth, (float)levtn, t0 ? 0.f : (float)exp(cbp), 0.f);
    if (k == 0) g_ecap[t] = t0 ? 1.f : (float)exp((double)lca_p);
  }
  if (e == 0) {
    double lcaT = g_sched[2 * T_STEPS + T_STEPS - 1];
    double l1caT = g_sched[3 * T_STEPS + T_STEPS - 1];
    double s = 0.0;
    for (int f = 0; f < N_FCAT; ++f) {
      double logK = log((double)c_numc[f]);
      double cbT = l1caT - logK;
      double qh = lad(lcaT, cbT);
      double qn = lad((double)NEGL + lcaT, cbT);
      s += exp(qh) * (qh + logK) + (double)(c_numc[f] - 1) * exp(qn) * (qn + logK);
    }
    g_klp = (float)s;
  }
}

// ---- DPP reductions. ctl is a TEMPLATE parameter (mov_dpp needs an immediate).
// 8-lane: xor1 (0xB1) + xor2 (0x4E) + row_half_mirror (0x141). 4-lane: xor1 +
// xor2. 2-lane: xor1 only. All strictly within their lane group. ----
template <int CTL>
__device__ __forceinline__ float dpp_add(float v) {
  return v + __int_as_float(__builtin_amdgcn_mov_dpp(__float_as_int(v), CTL, 0xF, 0xF, true));
}
__device__ __forceinline__ float osum(float v) {
  v = dpp_add<0xB1>(v); v = dpp_add<0x4E>(v); v = dpp_add<0x141>(v);
  return v;
}
__device__ __forceinline__ float qsum4(float v) {
  v = dpp_add<0xB1>(v); v = dpp_add<0x4E>(v);
  return v;
}
__device__ __forceinline__ float dsum2(float v) {
  return dpp_add<0xB1>(v);
}
template <int CTL>
__device__ __forceinline__ void argmax_step(float& smax, int& jm) {
  float os = __int_as_float(__builtin_amdgcn_mov_dpp(__float_as_int(smax), CTL, 0xF, 0xF, true));
  int   oj = __builtin_amdgcn_mov_dpp(jm, CTL, 0xF, 0xF, true);
  if (os > smax || (os == smax && oj < jm)) { smax = os; jm = oj; }
}
__device__ __forceinline__ void oargmax(float& smax, int& jm) {
  argmax_step<0xB1>(smax, jm); argmax_step<0x4E>(smax, jm); argmax_step<0x141>(smax, jm);
}
__device__ __forceinline__ void qargmax4(float& smax, int& jm) {
  argmax_step<0xB1>(smax, jm); argmax_step<0x4E>(smax, jm);
}
__device__ __forceinline__ void dargmax2(float& smax, int& jm) {
  argmax_step<0xB1>(smax, jm);
}
__device__ __forceinline__ float mirror16_add(float v) { return dpp_add<0x140>(v); }
__device__ __forceinline__ float halfmirror_add(float v) { return dpp_add<0x141>(v); }
__device__ __forceinline__ float xor2_add(float v) { return dpp_add<0x4E>(v); }

// Generic packed-feature body: LANES lanes per feature (8, 4, or 2),
// compile-time NJ, runtime K/off/h/table (group-selected by caller).
// CACHE=false (only the NJ7 (50|40) block) skips the persistent exp-cache:
// pass 2 reloads x (L1-hot) and recomputes __expf -- identical input ->
// identical value; trims ~7 VGPR at the kernel's register peak.
// Element arithmetic and decision path (clamp -> precise logf gumbel ->
// score select -> ascending-j strict-max, min-index cross-lane tiebreak)
// bit-identical to all passing rounds; argmax is partition-independent.
template <int LANES, int NJ, bool CACHE = true>
__device__ __forceinline__ float packed_body(int g, int K, int off, int h, bool t0, float ecap,
                                             const float* __restrict__ mocat,
                                             const float* __restrict__ urow,
                                             const float4* __restrict__ tb)
{
  float4 ta = tb[0], tbv = tb[1], tc = tb[2];
  float ev_h = ta.x, ev_n = ta.y, q1h = ta.z, q1n = ta.w;
  float q1he = tbv.x, q1ne = tbv.y, eth = tbv.z, etn = tbv.w;
  float levth = tc.x, levtn = tc.y, cbpe = tc.z;

  float xv[CACHE ? NJ : 1];
  if (CACHE) {
    #pragma unroll
    for (int jj = 0; jj < NJ; ++jj) {
      int j = jj * LANES + g;
      int jc = (j < K) ? j : (K - 1);
      xv[jj] = mocat[off + jc];
    }
  }

  // ---- pass 1: sum exp(model_out) + gumbel-score argmax ----
  float s1 = 0.f, smax = NINF;
  int jm = 0x7fffffff;
  #pragma unroll
  for (int jj = 0; jj < NJ; ++jj) {
    int j = jj * LANES + g;
    int jc = (j < K) ? j : (K - 1);
    bool in = (j < K);
    float x = CACHE ? xv[jj] : mocat[off + jc];
    float e = __expf(x);
    if (CACHE) xv[jj] = e;                    // cache exp for pass 2
    s1 += in ? e : 0.f;
    float u = urow[off + jc];
    u = fminf(fmaxf(u, 1e-30f), 1.0f);
    float gum = -logf(-logf(u));
    float sc = ((j == h) ? ev_h : ev_n) + gum;
    if (in && sc > smax) { smax = sc; jm = j; }
  }
  if (LANES == 8)      { s1 = osum(s1);  oargmax(smax, jm); }
  else if (LANES == 4) { s1 = qsum4(s1); qargmax4(smax, jm); }
  else                 { s1 = dsum2(s1); dargmax2(smax, jm); }

  float ca = ecap * __builtin_amdgcn_rcpf(s1);  // exp(lca_{t-1}) / sum(exp(mocat))

  // ---- pass 2: E_j = exp(lev_m_j); linear-space accumulation ----
  float Sm = 0.f, Bv = 0.f, lmh = 0.f;
  #pragma unroll
  for (int jj = 0; jj < NJ; ++jj) {
    int j = jj * LANES + g;
    int jc = (j < K) ? j : (K - 1);
    bool in = (j < K);
    float e = CACHE ? xv[jj] : __expf(mocat[off + jc]);
    float E = fmaf(e, ca, cbpe);             // e^{lr+lca_p} + e^{cb_p}
    float lm = __logf(E);                    // lev_m_j
    float qe = (j == jm) ? q1he : q1ne;      // e^{q1_j}
    Sm = in ? fmaf(E, qe, Sm) : Sm;          // sum e^{un_m}
    float c = ((j == h) ? eth : etn) * qe;   // e^{un_t_j}
    Bv = in ? fmaf(c, lm, Bv) : Bv;          // sum e^{un_t} * lev_m
    lmh += (in && j == h) ? lm : 0.f;
  }
  if (LANES == 8)      { Sm = osum(Sm);  Bv = osum(Bv);  lmh = osum(lmh); }
  else if (LANES == 4) { Sm = qsum4(Sm); Bv = qsum4(Bv); lmh = qsum4(lmh); }
  else                 { Sm = dsum2(Sm); Bv = dsum2(Bv); lmh = dsum2(lmh); }

  float lse_m = __logf(Sm);
  bool hm = (h == jm);
  float Kf2 = (float)K - 2.f + (hm ? 1.f : 0.f);
  float coefH = eth * (hm ? q1he : q1ne);
  float coefJ = hm ? 0.f : etn * q1he;
  float cn = etn * q1ne;
  float A  = cn * levtn * Kf2 + coefH * levth + coefJ * levtn;  // sum e^{un_t} * levt
  float St = cn * Kf2 + coefH + coefJ;                          // sum e^{un_t}
  float kl = (A - Bv) * __builtin_amdgcn_rcpf(St) - __logf(St) + lse_m;
  float unh = lmh + (hm ? q1h : q1n);
  float dec = lse_m - unh;
  return t0 ? dec : kl;
}

__global__ __launch_bounds__(256) void gmd_kernel(
    const int* __restrict__ xci, const int* __restrict__ tarr,
    const float* __restrict__ noise, const float* __restrict__ ucat,
    const float* __restrict__ mo, float* __restrict__ out)
{
  int tid = blockIdx.x * blockDim.x + threadIdx.x;
  int row    = tid >> 4;       // 16 threads per row
  int lane16 = tid & 15;
  int g      = tid & 7;        // position within 8-lane group
  int g4     = tid & 3;        // position within 4-lane quad
  int g2     = tid & 1;        // position within 2-lane duo
  int sel    = (lane16 >> 3);  // pair select 0..1
  int qsel   = (lane16 >> 2);  // quad select 0..3
  int osel   = (lane16 >> 1);  // duo select 0..7
  if (row >= B_ROWS) return;

  int t = tarr[row];
  bool t0 = (t == 0);
  float ecap = g_ecap[t];
  const float4* tabt = g_tab4 + (size_t)t * NKID * 3;
  const int* xrow = xci + (size_t)row * N_FCAT;

  const float* morow = mo + (size_t)row * MO_STRIDE;
  const float* mocat = morow + NUM_NUM;
  const float* urow  = ucat + (size_t)row * N_DCAT;

  // Gaussian part: 1 of 16 elements per lane
  float gauss;
  {
    float d = noise[row * NUM_NUM + lane16] - morow[lane16];
    gauss = d * d;
  }

  // ---- 8-lane pairs: (32|24),(20|16) NJ4 descriptor LOOP (register fence --
  // r19 showed splitting it costs +16 VGPR); (16|12) NJ2; (50|40) NJ7
  // no-cache (the single change vs r18: trims xv[7] at the register peak) ----
  float multi8 = 0.f;
  #pragma unroll 1
  for (int p = 0; p < 2; ++p)
    multi8 += packed_body<8,4>(g, p4K[p][sel], p4OFF[p][sel], xrow[p4F[p][sel]],
                               t0, ecap, mocat, urow, tabt + p4KID[p][sel] * 3);
  multi8 += packed_body<8,2>(g, sel ? 12 : 16, sel ? 50 : 78, xrow[sel ? 9 : 11],
                             t0, ecap, mocat, urow, tabt + (sel ? 7 : 8) * 3);
  multi8 += packed_body<8,7,false>(g, sel ? 40 : 50, sel ? 170 : 248, xrow[sel ? 15 : 23],
                                   t0, ecap, mocat, urow, tabt + (sel ? 12 : 13) * 3);

  // ---- 4-lane quads: (10,10,10,8) NJ3; (8,6,6,2) NJ2 ----
  float multi4 = 0.f;
  multi4 += packed_body<4,3>(g4, qAK[qsel], qAOFF[qsel], xrow[qAF[qsel]],
                             t0, ecap, mocat, urow, tabt + qAKID[qsel] * 3);
  multi4 += packed_body<4,2>(g4, qBK[qsel], qBOFF[qsel], xrow[qBF[qsel]],
                             t0, ecap, mocat, urow, tabt + qBKID[qsel] * 3);

  // ---- 2-lane duos: (5,5,4,4,3,3,2,2) NJ3 -- one block, 8 features ----
  float multi2 = packed_body<2,3>(g2, dK[osel], dOFF[osel], xrow[dF[osel]],
                                  t0, ecap, mocat, urow, tabt + dKID[osel] * 3);

  // ---- combines (each partial held group-uniform; merge up the hierarchy) ----
  multi8 = mirror16_add(multi8);                      // A + B groups
  multi4 = mirror16_add(halfmirror_add(multi4));      // 4 quads
  multi2 = mirror16_add(halfmirror_add(xor2_add(multi2)));  // 8 duos
  float multi = multi8 + multi4 + multi2;

  gauss = osum(gauss);                  // within-8 sums
  gauss = mirror16_add(gauss);          // + other 8 -> all 16 elements

  if (lane16 == 0) out[row] = (multi * 1000.f + g_klp) / 24.f + gauss / 16.f;
}

extern "C" void kernel_launch(void* const* d_in, const int* in_sizes, int n_in,
                              void* d_out, int out_size, void* d_ws, size_t ws_size,
                              hipStream_t stream) {
  const int*   xci   = (const int*)d_in[0];
  const int*   tarr  = (const int*)d_in[1];
  const float* noise = (const float*)d_in[2];
  const float* ucat  = (const float*)d_in[3];
  const float* mo    = (const float*)d_in[4];
  float* out = (float*)d_out;
  (void)d_ws; (void)ws_size;

  hipLaunchKernelGGL(build_sched_kernel, dim3(1), dim3(1024), 0, stream);
  hipLaunchKernelGGL(build_tab_kernel, dim3((T_STEPS * NKID + 255) / 256), dim3(256), 0, stream);
  hipLaunchKernelGGL(gmd_kernel, dim3((B_ROWS * 16) / 256), dim3(256), 0, stream,
                     xci, tarr, noise, ucat, mo, out);
}

// Round 21
// 99.170 us; speedup vs baseline: 1.0796x; 1.0124x over previous
//
#include <hip/hip_runtime.h>
#include <math.h>

#define T_STEPS 1000
#define B_ROWS 65536
#define N_FCAT 24
#define N_DCAT 298
#define NUM_NUM 16
#define MO_STRIDE 314
#define NKID 14
#define NEGL -69.07755278982137f   // log(float32(1e-30))
#define NINF -1e38f

__constant__ int c_numc[N_FCAT] = {2,2,3,4,5,6,8,10,10,12,16,16,20,24,32,40,2,3,4,5,6,8,10,50};
__constant__ int c_kval[NKID]   = {2,3,4,5,6,8,10,12,16,20,24,32,40,50};

// 8-lane pair descriptors (sel = lane16>>3)
__constant__ int p4K[2][2]   = {{32,24},{20,16}};
__constant__ int p4OFF[2][2] = {{138,114},{94,62}};
__constant__ int p4KID[2][2] = {{11,10},{9,8}};
__constant__ int p4F[2][2]   = {{14,13},{12,10}};

// 4-lane quad descriptors (qsel = lane16>>2)
__constant__ int qAK[4]   = {10,10,10,8};
__constant__ int qAOFF[4] = {30,40,238,22};
__constant__ int qAKID[4] = {6,6,6,5};
__constant__ int qAF[4]   = {7,8,22,6};

__constant__ int qBK[4]   = {8,6,6,2};
__constant__ int qBOFF[4] = {230,16,224,210};
__constant__ int qBKID[4] = {5,4,4,0};
__constant__ int qBF[4]   = {21,5,20,16};

// 2-lane duo descriptors (osel = lane16>>1): 8 smallest features in one block
__constant__ int dK[8]   = {5,5,4,4,3,3,2,2};
__constant__ int dOFF[8] = {11,219,7,215,4,212,0,2};
__constant__ int dKID[8] = {3,3,2,2,1,1,0,0};
__constant__ int dF[8]   = {4,19,3,18,2,17,0,1};

// persistent module-owned tables, rebuilt deterministically every launch
__device__ float  g_sched[4*T_STEPS];      // LA | L1A | LCA | L1CA
__device__ float  g_ecap[T_STEPS];         // exp(LCA[t-1]) (1.0 at t=0)
__device__ float4 g_tab4[T_STEPS*NKID*3];  // per (t,kidx): 12 floats
__device__ float  g_klp;                   // sum over features of kl_prior

__device__ __forceinline__ float lae(float a, float b) {   // precise f32 (argmax path)
  float m = fmaxf(a, b);
  return m + logf(expf(a - m) + expf(b - m));
}
__device__ __forceinline__ double lad(double a, double b) {
  double m = fmax(a, b);
  return m + log(exp(a - m) + exp(b - m));
}

__global__ void build_sched_kernel() {
  __shared__ double sh[1024];
  int i = threadIdx.x;
  double la = 0.0;
  if (i < T_STEPS) {
    const double PI = 3.14159265358979323846;
    double u0 = (double)i / 1000.0, u1 = (double)(i + 1) / 1000.0;
    double c0 = cos((u0 + 0.008) / 1.008 * PI * 0.5);
    double c1 = cos((u1 + 0.008) / 1.008 * PI * 0.5);
    double beta = 1.0 - (c1 * c1) / (c0 * c0);
    if (beta > 0.2) beta = 0.2;
    la = log(1.0 - beta);
  }
  sh[i] = la;
  __syncthreads();
  double run = la;
  for (int ofs = 1; ofs < 1024; ofs <<= 1) {
    double add = (i >= ofs) ? sh[i - ofs] : 0.0;
    __syncthreads();
    run += add;
    sh[i] = run;
    __syncthreads();
  }
  if (i < T_STEPS) {
    g_sched[i]               = (float)la;
    g_sched[T_STEPS + i]     = (float)log(-expm1(la));
    g_sched[2 * T_STEPS + i] = (float)run;
    g_sched[3 * T_STEPS + i] = (float)log(-expm1(run));
  }
}

__global__ void build_tab_kernel() {
  int e = blockIdx.x * blockDim.x + threadIdx.x;
  if (e < T_STEPS * NKID) {
    int t = e / NKID, k = e - t * NKID;
    bool t0 = (t == 0);
    int tm1 = t0 ? 0 : t - 1;
    float la = g_sched[t], l1a = g_sched[T_STEPS + t];
    float lca = g_sched[2 * T_STEPS + t], l1ca = g_sched[3 * T_STEPS + t];
    float lca_p = g_sched[2 * T_STEPS + tm1], l1ca_p = g_sched[3 * T_STEPS + tm1];
    float logK = (float)log((double)c_kval[k]);
    // ---- argmax-critical: identical f32 sequence to the verified round-1 kernel ----
    float cb_t = l1ca - logK;
    float ev_h = lae(lca, cb_t);
    float ev_n = lae(NEGL + lca, cb_t);
    // ---- value path: double precision ----
    double cb1 = (double)l1a - (double)logK;
    double q1h = lad((double)la, cb1);
    double q1n = lad((double)NEGL + (double)la, cb1);
    double cbp = (double)l1ca_p - (double)logK;
    double levth = t0 ? 0.0 : lad((double)lca_p, cbp);
    double levtn = t0 ? (double)NEGL : lad((double)NEGL + (double)lca_p, cbp);
    float4* o = g_tab4 + e * 3;
    o[0] = make_float4(ev_h, ev_n, (float)q1h, (float)q1n);
    o[1] = make_float4((float)exp(q1h), (float)exp(q1n), (float)exp(levth), (float)exp(levtn));
    o[2] = make_float4((float)levth, (float)levtn, t0 ? 0.f : (float)exp(cbp), 0.f);
    if (k == 0) g_ecap[t] = t0 ? 1.f : (float)exp((double)lca_p);
  }
  if (e == 0) {
    double lcaT = g_sched[2 * T_STEPS + T_STEPS - 1];
    double l1caT = g_sched[3 * T_STEPS + T_STEPS - 1];
    double s = 0.0;
    for (int f = 0; f < N_FCAT; ++f) {
      double logK = log((double)c_numc[f]);
      double cbT = l1caT - logK;
      double qh = lad(lcaT, cbT);
      double qn = lad((double)NEGL + lcaT, cbT);
      s += exp(qh) * (qh + logK) + (double)(c_numc[f] - 1) * exp(qn) * (qn + logK);
    }
    g_klp = (float)s;
  }
}

// ---- DPP reductions. ctl is a TEMPLATE parameter (mov_dpp needs an immediate).
// 8-lane: xor1 (0xB1) + xor2 (0x4E) + row_half_mirror (0x141). 4-lane: xor1 +
// xor2. 2-lane: xor1 only. All strictly within their lane group. ----
template <int CTL>
__device__ __forceinline__ float dpp_add(float v) {
  return v + __int_as_float(__builtin_amdgcn_mov_dpp(__float_as_int(v), CTL, 0xF, 0xF, true));
}
__device__ __forceinline__ float osum(float v) {
  v = dpp_add<0xB1>(v); v = dpp_add<0x4E>(v); v = dpp_add<0x141>(v);
  return v;
}
__device__ __forceinline__ float qsum4(float v) {
  v = dpp_add<0xB1>(v); v = dpp_add<0x4E>(v);
  return v;
}
__device__ __forceinline__ float dsum2(float v) {
  return dpp_add<0xB1>(v);
}
template <int CTL>
__device__ __forceinline__ void argmax_step(float& smax, int& jm) {
  float os = __int_as_float(__builtin_amdgcn_mov_dpp(__float_as_int(smax), CTL, 0xF, 0xF, true));
  int   oj = __builtin_amdgcn_mov_dpp(jm, CTL, 0xF, 0xF, true);
  if (os > smax || (os == smax && oj < jm)) { smax = os; jm = oj; }
}
__device__ __forceinline__ void oargmax(float& smax, int& jm) {
  argmax_step<0xB1>(smax, jm); argmax_step<0x4E>(smax, jm); argmax_step<0x141>(smax, jm);
}
__device__ __forceinline__ void qargmax4(float& smax, int& jm) {
  argmax_step<0xB1>(smax, jm); argmax_step<0x4E>(smax, jm);
}
__device__ __forceinline__ void dargmax2(float& smax, int& jm) {
  argmax_step<0xB1>(smax, jm);
}
__device__ __forceinline__ float mirror16_add(float v) { return dpp_add<0x140>(v); }
__device__ __forceinline__ float halfmirror_add(float v) { return dpp_add<0x141>(v); }
__device__ __forceinline__ float xor2_add(float v) { return dpp_add<0x4E>(v); }

// Generic packed-feature body: LANES lanes per feature (8, 4, or 2),
// compile-time NJ, runtime K/off/h/table (group-selected by caller).
// Element arithmetic and decision path (clamp -> precise logf gumbel ->
// score select -> ascending-j strict-max, min-index cross-lane tiebreak)
// bit-identical to all passing rounds; argmax is partition-independent.
template <int LANES, int NJ>
__device__ __forceinline__ float packed_body(int g, int K, int off, int h, bool t0, float ecap,
                                             const float* __restrict__ mocat,
                                             const float* __restrict__ urow,
                                             const float4* __restrict__ tb)
{
  float4 ta = tb[0], tbv = tb[1], tc = tb[2];
  float ev_h = ta.x, ev_n = ta.y, q1h = ta.z, q1n = ta.w;
  float q1he = tbv.x, q1ne = tbv.y, eth = tbv.z, etn = tbv.w;
  float levth = tc.x, levtn = tc.y, cbpe = tc.z;

  float xv[NJ];
  #pragma unroll
  for (int jj = 0; jj < NJ; ++jj) {
    int j = jj * LANES + g;
    int jc = (j < K) ? j : (K - 1);
    xv[jj] = mocat[off + jc];
  }

  // ---- pass 1: sum exp(model_out) + gumbel-score argmax ----
  float s1 = 0.f, smax = NINF;
  int jm = 0x7fffffff;
  #pragma unroll
  for (int jj = 0; jj < NJ; ++jj) {
    int j = jj * LANES + g;
    int jc = (j < K) ? j : (K - 1);
    bool in = (j < K);
    float e = __expf(xv[jj]);
    xv[jj] = e;                               // cache exp for pass 2
    s1 += in ? e : 0.f;
    float u = urow[off + jc];
    u = fminf(fmaxf(u, 1e-30f), 1.0f);
    float gum = -logf(-logf(u));
    float sc = ((j == h) ? ev_h : ev_n) + gum;
    if (in && sc > smax) { smax = sc; jm = j; }
  }
  if (LANES == 8)      { s1 = osum(s1);  oargmax(smax, jm); }
  else if (LANES == 4) { s1 = qsum4(s1); qargmax4(smax, jm); }
  else                 { s1 = dsum2(s1); dargmax2(smax, jm); }

  float ca = ecap * __builtin_amdgcn_rcpf(s1);  // exp(lca_{t-1}) / sum(exp(mocat))

  // ---- pass 2: E_j = exp(lev_m_j); linear-space accumulation from cached exp ----
  float Sm = 0.f, Bv = 0.f, lmh = 0.f;
  #pragma unroll
  for (int jj = 0; jj < NJ; ++jj) {
    int j = jj * LANES + g;
    bool in = (j < K);
    float E = fmaf(xv[jj], ca, cbpe);        // e^{lr+lca_p} + e^{cb_p}
    float lm = __logf(E);                    // lev_m_j
    float qe = (j == jm) ? q1he : q1ne;      // e^{q1_j}
    Sm = in ? fmaf(E, qe, Sm) : Sm;          // sum e^{un_m}
    float c = ((j == h) ? eth : etn) * qe;   // e^{un_t_j}
    Bv = in ? fmaf(c, lm, Bv) : Bv;          // sum e^{un_t} * lev_m
    lmh += (in && j == h) ? lm : 0.f;
  }
  if (LANES == 8)      { Sm = osum(Sm);  Bv = osum(Bv);  lmh = osum(lmh); }
  else if (LANES == 4) { Sm = qsum4(Sm); Bv = qsum4(Bv); lmh = qsum4(lmh); }
  else                 { Sm = dsum2(Sm); Bv = dsum2(Bv); lmh = dsum2(lmh); }

  float lse_m = __logf(Sm);
  bool hm = (h == jm);
  float Kf2 = (float)K - 2.f + (hm ? 1.f : 0.f);
  float coefH = eth * (hm ? q1he : q1ne);
  float coefJ = hm ? 0.f : etn * q1he;
  float cn = etn * q1ne;
  float A  = cn * levtn * Kf2 + coefH * levth + coefJ * levtn;  // sum e^{un_t} * levt
  float St = cn * Kf2 + coefH + coefJ;                          // sum e^{un_t}
  float kl = (A - Bv) * __builtin_amdgcn_rcpf(St) - __logf(St) + lse_m;
  float unh = lmh + (hm ? q1h : q1n);
  float dec = lse_m - unh;
  return t0 ? dec : kl;
}

__global__ __launch_bounds__(256) void gmd_kernel(
    const int* __restrict__ xci, const int* __restrict__ tarr,
    const float* __restrict__ noise, const float* __restrict__ ucat,
    const float* __restrict__ mo, float* __restrict__ out)
{
  int tid = blockIdx.x * blockDim.x + threadIdx.x;
  int row    = tid >> 4;       // 16 threads per row
  int lane16 = tid & 15;
  int g      = tid & 7;        // position within 8-lane group
  int g4     = tid & 3;        // position within 4-lane quad
  int g2     = tid & 1;        // position within 2-lane duo
  int sel    = (lane16 >> 3);  // pair select 0..1
  int qsel   = (lane16 >> 2);  // quad select 0..3
  int osel   = (lane16 >> 1);  // duo select 0..7
  if (row >= B_ROWS) return;

  int t = tarr[row];
  bool t0 = (t == 0);
  float ecap = g_ecap[t];
  const float4* tabt = g_tab4 + (size_t)t * NKID * 3;
  const int* xrow = xci + (size_t)row * N_FCAT;

  const float* morow = mo + (size_t)row * MO_STRIDE;
  const float* mocat = morow + NUM_NUM;
  const float* urow  = ucat + (size_t)row * N_DCAT;

  // Gaussian part: 1 of 16 elements per lane
  float gauss;
  {
    float d = noise[row * NUM_NUM + lane16] - morow[lane16];
    gauss = d * d;
  }

  // ---- 8-lane pairs: (32|24),(20|16) NJ4 loop; (16|12) NJ2; (50|40) NJ7 ----
  float multi8 = 0.f;
  #pragma unroll 1
  for (int p = 0; p < 2; ++p)
    multi8 += packed_body<8,4>(g, p4K[p][sel], p4OFF[p][sel], xrow[p4F[p][sel]],
                               t0, ecap, mocat, urow, tabt + p4KID[p][sel] * 3);
  multi8 += packed_body<8,2>(g, sel ? 12 : 16, sel ? 50 : 78, xrow[sel ? 9 : 11],
                             t0, ecap, mocat, urow, tabt + (sel ? 7 : 8) * 3);
  multi8 += packed_body<8,7>(g, sel ? 40 : 50, sel ? 170 : 248, xrow[sel ? 15 : 23],
                             t0, ecap, mocat, urow, tabt + (sel ? 12 : 13) * 3);

  // ---- 4-lane quads: (10,10,10,8) NJ3; (8,6,6,2) NJ2 ----
  float multi4 = 0.f;
  multi4 += packed_body<4,3>(g4, qAK[qsel], qAOFF[qsel], xrow[qAF[qsel]],
                             t0, ecap, mocat, urow, tabt + qAKID[qsel] * 3);
  multi4 += packed_body<4,2>(g4, qBK[qsel], qBOFF[qsel], xrow[qBF[qsel]],
                             t0, ecap, mocat, urow, tabt + qBKID[qsel] * 3);

  // ---- 2-lane duos: (5,5,4,4,3,3,2,2) NJ3 -- one block, 8 features ----
  float multi2 = packed_body<2,3>(g2, dK[osel], dOFF[osel], xrow[dF[osel]],
                                  t0, ecap, mocat, urow, tabt + dKID[osel] * 3);

  // ---- combines (each partial held group-uniform; merge up the hierarchy) ----
  multi8 = mirror16_add(multi8);                      // A + B groups
  multi4 = mirror16_add(halfmirror_add(multi4));      // 4 quads
  multi2 = mirror16_add(halfmirror_add(xor2_add(multi2)));  // 8 duos
  float multi = multi8 + multi4 + multi2;

  gauss = osum(gauss);                  // within-8 sums
  gauss = mirror16_add(gauss);          // + other 8 -> all 16 elements

  if (lane16 == 0) out[row] = (multi * 1000.f + g_klp) / 24.f + gauss / 16.f;
}

extern "C" void kernel_launch(void* const* d_in, const int* in_sizes, int n_in,
                              void* d_out, int out_size, void* d_ws, size_t ws_size,
                              hipStream_t stream) {
  const int*   xci   = (const int*)d_in[0];
  const int*   tarr  = (const int*)d_in[1];
  const float* noise = (const float*)d_in[2];
  const float* ucat  = (const float*)d_in[3];
  const float* mo    = (const float*)d_in[4];
  float* out = (float*)d_out;
  (void)d_ws; (void)ws_size;

  hipLaunchKernelGGL(build_sched_kernel, dim3(1), dim3(1024), 0, stream);
  hipLaunchKernelGGL(build_tab_kernel, dim3((T_STEPS * NKID + 255) / 256), dim3(256), 0, stream);
  hipLaunchKernelGGL(gmd_kernel, dim3((B_ROWS * 16) / 256), dim3(256), 0, stream,
                     xci, tarr, noise, ucat, mo, out);
}